// Round 8
// baseline (291.341 us; speedup 1.0000x reference)
//
#include <hip/hip_runtime.h>

#define TOKENS 8192
#define D_IN   4096
#define D_OUT  4096

typedef _Float16 f16;
typedef __attribute__((ext_vector_type(8))) _Float16 half8;
typedef __attribute__((ext_vector_type(4))) float    f32x4;
typedef __attribute__((address_space(3))) char       lds_char;

// ---------------- conversion kernels ----------------

__global__ void cvt_x_kernel(const float* __restrict__ x, f16* __restrict__ xh) {
    size_t i = ((size_t)blockIdx.x * blockDim.x + threadIdx.x) * 4;
    float4 v = *reinterpret_cast<const float4*>(x + i);
    union { f16 h[4]; uint2 u; } p;
    p.h[0] = (f16)v.x; p.h[1] = (f16)v.y; p.h[2] = (f16)v.z; p.h[3] = (f16)v.w;
    *reinterpret_cast<uint2*>(xh + i) = p.u;
}

__global__ void cvt_w_kernel(const int* __restrict__ w, f16* __restrict__ wh,
                             const float* __restrict__ scale_p,
                             const int* __restrict__ zp_p) {
    size_t i = ((size_t)blockIdx.x * blockDim.x + threadIdx.x) * 4;
    float s = scale_p[0];
    float z = (float)zp_p[0];
    int4 v = *reinterpret_cast<const int4*>(w + i);
    union { f16 h[4]; uint2 u; } p;
    p.h[0] = (f16)(((float)v.x - z) * s);
    p.h[1] = (f16)(((float)v.y - z) * s);
    p.h[2] = (f16)(((float)v.z - z) * s);
    p.h[3] = (f16)(((float)v.w - z) * s);
    *reinterpret_cast<uint2*>(wh + i) = p.u;
}

// ---------------- GEMM: 256x256, BK=64, 8 waves, even 4/8/8/4 pipeline -----
// C[t][o] = sum_k A[t][k]*B[o][k];  A=[M][K] f16, B=[N][K] f16 (K-major).
// LDS: 2 dbuf x (A 32KB + B 32KB) = 128 KB, [256][64] f16 rows with XOR
// swizzle phys_colbyte = logical ^ ((row&7)<<4); global_load_lds writes
// linearly, swizzle pre-applied to the per-lane GLOBAL source column.
//
// R8 (post-mortem of R7's 12-read clump): reads spread 4/8/8/4 per phase,
// each batch issued ONE FULL MFMA CLUSTER (16 MFMA, ~620cy block-wide)
// before its consumer; staging in HALF-tiles (2 stage16 calls each) with
// >=2-phase lead to every drain. Steady-state tile t:
//  ph0: BAR; rd b1(t)[4];  stage Ah1(t+1), Bh0(t+1); MFMA Q00(a0,b0)
//  ph1: BAR; rd a1(t)[8];  stage Bh1(t+1);           MFMA Q01(a0,b1)
//  ph2: VMCNT(4); BAR; rd a0(t+1)[8];                MFMA Q11(a1,b1)
//       BAR; stage Ah0(t+2)   [BAR: all waves' Q11 consumed a1(t) before
//                              its buffer region (same parity) is rewritten]
//  ph3: VMCNT(2); BAR; rd b0n(t+1)[4];               MFMA Q10(a1,b0); b0=b0n
// vmcnt ledger (issue order Ah0',[Ah1',Bh0'],Bh1',Ah0''):
//  @ph2: P=[Ah0'2,Ah1'2,Bh0'2,Bh1'2]=8 -> VMCNT(4) retires A-halves, leaves B.
//  @ph3: P=[Bh0'2,Bh1'2,Ah0''2]=6      -> VMCNT(2) retires B, leaves Ah0''.
//  Never 0 in steady state. Tail: t=NT-2 skips Ah0'' -> ph3 VMCNT(0) (loads
//  >=1 phase old); t=NT-1 stages/reads nothing new, all pre-drained.
// Protocol (R5 lesson): drain own vmcnt -> s_barrier -> ds_read everywhere.

#define BM 256
#define BN 256
#define BK 64
#define NT (D_IN / BK)      // 64 K-tiles
#define LDS_BUF   65536
#define LDS_B_OFF 32768

__device__ __forceinline__ void stage16(const f16* g, lds_char* l) {
    __builtin_amdgcn_global_load_lds(
        (const __attribute__((address_space(1))) void*)g,
        (__attribute__((address_space(3))) void*)l, 16, 0, 0);
}

#define LDS_LOAD8(p) (*(const __attribute__((address_space(3))) half8*)(p))

#define LOAD_AQ(DST, BUF, QM)                                               \
    do { _Pragma("unroll")                                                  \
        for (int fm = 0; fm < 4; ++fm) {                                    \
            int rr = wr * 128 + (QM) * 64 + fm * 16 + lr;                   \
            _Pragma("unroll")                                               \
            for (int ks = 0; ks < 2; ++ks)                                  \
                DST[fm][ks] = LDS_LOAD8((BUF) + rr * 128 +                  \
                                        ((cb0 + ks * 64) ^ swzr));          \
        } } while (0)

#define LOAD_BQ(DST, BUF, QN)                                               \
    do { _Pragma("unroll")                                                  \
        for (int fn = 0; fn < 2; ++fn) {                                    \
            int rr = wc * 64 + (QN) * 32 + fn * 16 + lr;                    \
            _Pragma("unroll")                                               \
            for (int ks = 0; ks < 2; ++ks)                                  \
                DST[fn][ks] = LDS_LOAD8((BUF) + rr * 128 +                  \
                                        ((cb0 + ks * 64) ^ swzr));          \
        } } while (0)

#define MFMA_Q(QM, QN, AV, BV)                                              \
    do { _Pragma("unroll")                                                  \
        for (int fm = 0; fm < 4; ++fm) {                                    \
            _Pragma("unroll")                                               \
            for (int fn = 0; fn < 2; ++fn) {                                \
                _Pragma("unroll")                                           \
                for (int ks = 0; ks < 2; ++ks)                              \
                    acc[(QM)*4+fm][(QN)*2+fn] =                             \
                        __builtin_amdgcn_mfma_f32_16x16x32_f16(             \
                            AV[fm][ks], BV[fn][ks],                         \
                            acc[(QM)*4+fm][(QN)*2+fn], 0, 0, 0);            \
            }                                                               \
        } } while (0)

#define BAR()      __builtin_amdgcn_s_barrier()
#define VMCNT(N)   asm volatile("s_waitcnt vmcnt(" #N ")" ::: "memory")
#define PRIO(x)    __builtin_amdgcn_s_setprio(x)

__global__ __launch_bounds__(512, 2)
void gemm_ev(const f16* __restrict__ A, const f16* __restrict__ B,
             const float* __restrict__ bias,
             const float* __restrict__ oscale_p, const int* __restrict__ ozp_p,
             float* __restrict__ C)
{
    __shared__ __align__(1024) char smem_[2 * LDS_BUF];   // 128 KiB
    lds_char* smem = (lds_char*)smem_;
    constexpr int K = D_IN, N = D_OUT;

    // XCD-aware bijective swizzle (grid = 512, divisible by 8)
    int nwg = gridDim.x;
    int cpx = nwg >> 3;
    int bid = blockIdx.x;
    int swz = (bid & 7) * cpx + (bid >> 3);
    int ntn = N / BN;                        // 16
    int m0 = (swz / ntn) * BM;
    int n0 = (swz % ntn) * BN;

    int tid = threadIdx.x;
    int l   = tid & 63;
    int wv  = tid >> 6;                      // 0..7
    int wr  = wv >> 2;                       // 0..1 (M)
    int wc  = wv & 3;                        // 0..3 (N)

    // staging: lane l -> row_in_block = l>>3, phys slot = l&7;
    // pre-swizzled global col = ((l&7) ^ (l>>3)) * 8 f16.
    int srow = wv * 8 + (l >> 3);
    int scol = ((l & 7) ^ (l >> 3)) * 8;
    const f16* gA = A + (size_t)(m0 + srow) * K + scol;
    const f16* gB = B + (size_t)(n0 + srow) * K + scol;
    lds_char* dstbase = smem + wv * 1024 + l * 16;

    // read-side per-lane constants
    int lr   = l & 15;
    int swzr = (l & 7) << 4;
    int cb0  = (l >> 4) * 16;

    f32x4 acc[8][4] = {};                    // [qm*4+fm][qn*2+fn]
    half8 a0[4][2], a1[4][2], b0[2][2], b0n[2][2], b1[2][2];

    // ---- prologue: stage tile0 (8) + Ah0(1) (2); retire tile0; preload a0,b0
    #pragma unroll
    for (int q = 0; q < 4; ++q) stage16(gA + (size_t)q * 64 * K, dstbase + q * 8192);
    #pragma unroll
    for (int q = 0; q < 4; ++q) stage16(gB + (size_t)q * 64 * K, dstbase + LDS_B_OFF + q * 8192);
    stage16(gA + (size_t)BK,                dstbase + LDS_BUF);          // Ah0(1) q0
    stage16(gA + (size_t)64 * K + BK,       dstbase + LDS_BUF + 8192);   // Ah0(1) q1
    VMCNT(2);   // retire tile0's 8, keep Ah0(1) in flight
    BAR();
    LOAD_AQ(a0, smem, 0);
    LOAD_BQ(b0, (smem + LDS_B_OFF), 0);

    for (int t = 0; t < NT; ++t) {
        const lds_char* bufA  = smem + (t & 1) * LDS_BUF;
        const lds_char* bufB  = bufA + LDS_B_OFF;
        const lds_char* bufAn = smem + ((t + 1) & 1) * LDS_BUF;
        const lds_char* bufBn = bufAn + LDS_B_OFF;
        lds_char* dst1 = dstbase + ((t + 1) & 1) * LDS_BUF;   // t+1 stages
        lds_char* dst2 = dstbase + (t & 1) * LDS_BUF;         // t+2 stages
        const f16* nA  = gA + (size_t)(t + 1) * BK;
        const f16* nB  = gB + (size_t)(t + 1) * BK;
        const f16* n2A = gA + (size_t)(t + 2) * BK;

        // ---- ph0: rd b1(t); stage Ah1(t+1), Bh0(t+1); MFMA Q00
        BAR();
        LOAD_BQ(b1, bufB, 1);
        if (t + 1 < NT) {
            stage16(nA + (size_t)128 * K, dst1 + 2 * 8192);              // Ah1 q2
            stage16(nA + (size_t)192 * K, dst1 + 3 * 8192);              // Ah1 q3
            stage16(nB,                   dst1 + LDS_B_OFF);             // Bh0 q0
            stage16(nB + (size_t)64 * K,  dst1 + LDS_B_OFF + 8192);      // Bh0 q1
        }
        PRIO(1); MFMA_Q(0, 0, a0, b0); PRIO(0);

        // ---- ph1: rd a1(t); stage Bh1(t+1); MFMA Q01
        BAR();
        LOAD_AQ(a1, bufA, 1);
        if (t + 1 < NT) {
            stage16(nB + (size_t)128 * K, dst1 + LDS_B_OFF + 2 * 8192);  // Bh1 q2
            stage16(nB + (size_t)192 * K, dst1 + LDS_B_OFF + 3 * 8192);  // Bh1 q3
        }
        PRIO(1); MFMA_Q(0, 1, a0, b1); PRIO(0);

        // ---- ph2: A(t+1) consume (drain->BAR->read); MFMA Q11; BAR; stage Ah0(t+2)
        VMCNT(4);     // retires Ah0(t+1), Ah1(t+1); leaves Bh0/Bh1(t+1)
        BAR();
        if (t + 1 < NT) LOAD_AQ(a0, bufAn, 0);
        PRIO(1); MFMA_Q(1, 1, a1, b1); PRIO(0);
        BAR();        // all waves consumed a1(t) -> safe to rewrite buf(t&1) A
        if (t + 2 < NT) {
            stage16(n2A,                  dst2);                         // Ah0 q0
            stage16(n2A + (size_t)64 * K, dst2 + 8192);                  // Ah0 q1
        }

        // ---- ph3: B(t+1) consume (drain->BAR->read); MFMA Q10; rotate b0
        if (t + 1 < NT) {
            if (t + 2 < NT) { VMCNT(2); } else { VMCNT(0); }
            BAR();
            LOAD_BQ(b0n, bufBn, 0);
            PRIO(1); MFMA_Q(1, 0, a1, b0); PRIO(0);
            #pragma unroll
            for (int fn = 0; fn < 2; ++fn)
                #pragma unroll
                for (int ks = 0; ks < 2; ++ks)
                    b0[fn][ks] = b0n[fn][ks];
        } else {
            BAR();
            PRIO(1); MFMA_Q(1, 0, a1, b0); PRIO(0);
        }
    }

    // ---- epilogue: bias + fake-quantize (round-half-even = jnp.round)
    float os  = oscale_p[0];
    float ozp = (float)ozp_p[0];
    float inv = 1.0f / os;
    #pragma unroll
    for (int qm = 0; qm < 2; ++qm) {
        #pragma unroll
        for (int fm = 0; fm < 4; ++fm) {
            int rowb = m0 + wr * 128 + qm * 64 + fm * 16 + (l >> 4) * 4;
            #pragma unroll
            for (int qn = 0; qn < 2; ++qn) {
                #pragma unroll
                for (int fn = 0; fn < 2; ++fn) {
                    int col = n0 + wc * 64 + qn * 32 + fn * 16 + lr;
                    float bv = bias[col];
                    f32x4 v = acc[qm * 4 + fm][qn * 2 + fn];
                    #pragma unroll
                    for (int j = 0; j < 4; ++j) {
                        float o = v[j] + bv;
                        float q = rintf(o * inv) + ozp;
                        q = fminf(fmaxf(q, 0.0f), 255.0f);
                        C[(size_t)(rowb + j) * N + col] = (q - ozp) * os;
                    }
                }
            }
        }
    }
}

// ---------------- launch ----------------

extern "C" void kernel_launch(void* const* d_in, const int* in_sizes, int n_in,
                              void* d_out, int out_size, void* d_ws, size_t ws_size,
                              hipStream_t stream) {
    const float* x      = (const float*)d_in[0];
    const int*   w8     = (const int*)d_in[1];
    const float* wscale = (const float*)d_in[2];
    const int*   wzp    = (const int*)d_in[3];
    const float* bias   = (const float*)d_in[4];
    const float* oscale = (const float*)d_in[5];
    const int*   ozp    = (const int*)d_in[6];
    float* out = (float*)d_out;

    const size_t x_elems = (size_t)TOKENS * D_IN;
    const size_t w_elems = (size_t)D_OUT * D_IN;
    const size_t need = (x_elems + w_elems) * sizeof(f16);
    if (ws_size < need) return;

    f16* xh = (f16*)d_ws;
    f16* wh = xh + x_elems;

    {
        int blocks = (int)(x_elems / 4 / 256);
        cvt_x_kernel<<<blocks, 256, 0, stream>>>(x, xh);
    }
    {
        int blocks = (int)(w_elems / 4 / 256);
        cvt_w_kernel<<<blocks, 256, 0, stream>>>(w8, wh, wscale, wzp);
    }
    {
        int grid = (TOKENS / BM) * (D_OUT / BN);   // 32 * 16 = 512, %8 == 0
        gemm_ev<<<grid, 512, 0, stream>>>(xh, wh, bias, oscale, ozp, out);
    }
}